// Round 8
// baseline (2062.199 us; speedup 1.0000x reference)
//
#include <hip/hip_runtime.h>

typedef unsigned int uint;
typedef unsigned long long ull;

#define USER_NUM   100000
#define ITEM_NUM   50000
#define N_NODES    (USER_NUM + ITEM_NUM)
#define NNZ        4800000
#define EMB        64
#define EPS_F      0.2f
#define NORM_EPS_F 1e-12f

// buckets of 256 rows
#define RB_SHIFT   8
#define RB         256
#define NB         ((N_NODES + RB - 1) / RB)     // 586
#define CAP        9216                           // mean 8191, std ~90 -> +11 sigma
#define BINA_CHUNK 4096
#define BINA_GRID  ((NNZ + BINA_CHUNK - 1) / BINA_CHUNK)  // 1172
#define BB_K       9                              // ceil(CAP / 1024)

// fused persistent spmm
#define SPMM_BLOCKS 1792                          // cap 8/CU = 2048 -> 256-block slack
#define SPMM_WAVES  (SPMM_BLOCKS * 4)             // 7168
#define BAR_STRIDE  256                           // ints per barrier (16 ctr * 16 ints)

// ---------------- bf16 helpers ----------------
__device__ inline float bflo(uint u) { return __uint_as_float(u << 16); }
__device__ inline float bfhi(uint u) { return __uint_as_float(u & 0xffff0000u); }
__device__ inline uint f2bf(float f) {                 // RNE round to bf16
    uint u = __float_as_uint(f);
    return (u + 0x7fffu + ((u >> 16) & 1u)) >> 16;
}
__device__ inline uint pack2(float a, float b) { return f2bf(a) | (f2bf(b) << 16); }

// ---------------- CSR build ----------------

// Phase A: block-level LDS counting sort by bucket (gcount zero-initialized by
// hipMemsetAsync; staging position = b*CAP + fetch-added count). Convert
// (fp32 concat -> bf16 pack) fused as a tail so it costs no extra dispatch.
__global__ __launch_bounds__(512) void binA_kernel(const int* __restrict__ rows,
                                                   const int* __restrict__ cols,
                                                   const float* __restrict__ vals,
                                                   int* __restrict__ gcount,
                                                   int2* __restrict__ staging,
                                                   const float4* __restrict__ uemb,
                                                   const float4* __restrict__ iemb,
                                                   uint2* __restrict__ xh) {
    __shared__ int2 data[BINA_CHUNK];            // 32 KB
    __shared__ unsigned short bid[BINA_CHUNK];   // 8 KB
    __shared__ int hist[NB];
    __shared__ int rstart[NB + 1];
    __shared__ int gbase[NB];
    __shared__ int lcur[NB];
    __shared__ int wsum[8];
    int t = threadIdx.x;
    int cbeg = blockIdx.x * BINA_CHUNK;
    int cend = min(cbeg + BINA_CHUNK, NNZ);
    int total = cend - cbeg;

    int r[8], c[8];
    float v[8];
    if (t < NB) hist[t] = 0;
    if (t + 512 < NB) hist[t + 512] = 0;
    __syncthreads();
#pragma unroll
    for (int k = 0; k < 8; ++k) {
        int i = cbeg + (k << 9) + t;
        bool ok = i < cend;
        r[k] = ok ? rows[i] : -1;
        c[k] = ok ? cols[i] : 0;
        v[k] = ok ? vals[i] : 0.f;
    }
#pragma unroll
    for (int k = 0; k < 8; ++k)
        if (r[k] >= 0) atomicAdd(&hist[r[k] >> RB_SHIFT], 1);
    __syncthreads();

    // pair-per-thread hierarchical shfl scan over 1024 slots (NB=586)
    int v0 = (2 * t < NB) ? hist[2 * t] : 0;
    int v1 = (2 * t + 1 < NB) ? hist[2 * t + 1] : 0;
    int pv = v0 + v1;
    int sc = pv;
#pragma unroll
    for (int off = 1; off < 64; off <<= 1) {
        int u = __shfl_up(sc, off, 64);
        if ((t & 63) >= off) sc += u;
    }
    if ((t & 63) == 63) wsum[t >> 6] = sc;
    __syncthreads();
    if (t < 64) {
        int ws = (t < 8) ? wsum[t] : 0;
#pragma unroll
        for (int off = 1; off < 8; off <<= 1) {
            int u = __shfl_up(ws, off, 64);
            if (t >= off) ws += u;
        }
        if (t < 8) wsum[t] = ws;
    }
    __syncthreads();
    int wid = t >> 6;
    int ex = sc - pv + ((wid > 0) ? wsum[wid - 1] : 0);
    if (2 * t <= NB) rstart[2 * t] = ex;
    if (2 * t + 1 <= NB) rstart[2 * t + 1] = ex + v0;
    if (2 * t < NB) {
        gbase[2 * t] = (2 * t) * CAP + atomicAdd(&gcount[2 * t], v0);
        lcur[2 * t] = 0;
    }
    if (2 * t + 1 < NB) {
        gbase[2 * t + 1] = (2 * t + 1) * CAP + atomicAdd(&gcount[2 * t + 1], v1);
        lcur[2 * t + 1] = 0;
    }
    __syncthreads();

    // sort into LDS by bucket, recording bucket id per slot
#pragma unroll
    for (int k = 0; k < 8; ++k) {
        if (r[k] >= 0) {
            int b = r[k] >> RB_SHIFT;
            int pos = rstart[b] + atomicAdd(&lcur[b], 1);
            data[pos] = make_int2(((r[k] & (RB - 1)) << 18) | c[k],
                                  __float_as_int(v[k]));
            bid[pos] = (unsigned short)b;
        }
    }
    __syncthreads();

    // sequential copy-out: consecutive threads -> consecutive global addresses
    for (int i = t; i < total; i += 512) {
        int b = bid[i];
        staging[(long)gbase[b] + (i - rstart[b])] = data[i];
    }

    // ---- fused convert tail (independent work, no barrier needed) ----
    const int NU4 = USER_NUM * EMB / 4;
    const int NT4 = N_NODES * EMB / 4;
    int stride = gridDim.x * blockDim.x;
    for (int i = blockIdx.x * blockDim.x + t; i < NT4; i += stride) {
        float4 f = (i < NU4) ? uemb[i] : iemb[i - NU4];
        xh[i] = make_uint2(pack2(f.x, f.y), pack2(f.z, f.w));
    }
}

// Phase B: one 1024-thread block per 256-row bucket. Bucket-base prefix sum
// computed in-block (bscan kernel folded in: redundant 586-int scan, ~300cy).
// Staging read once into registers; LDS counting sort; sequential copy-out.
__global__ __launch_bounds__(1024) void binB_kernel(const int* __restrict__ gcount,
                                                    const int2* __restrict__ staging,
                                                    int2* __restrict__ edges,
                                                    int* __restrict__ row_ptr) {
    __shared__ int2 sorted[CAP];      // 72 KB
    __shared__ int s[RB];
    __shared__ int cur[RB];
    __shared__ int wsum[16];
    __shared__ int base_sh;
    int b = blockIdx.x;
    int t = threadIdx.x;
    int cnt = gcount[b];
    long sbase = (long)b * CAP;

    int2 e[BB_K];
    if (t < RB) s[t] = 0;
#pragma unroll
    for (int k = 0; k < BB_K; ++k) {
        int i = (k << 10) + t;
        e[k] = (i < cnt) ? staging[sbase + i] : make_int2(-1, 0);
    }

    // in-block exclusive scan of bucket counts -> base for this bucket
    int c0 = (2 * t < NB) ? gcount[2 * t] : 0;
    int c1 = (2 * t + 1 < NB) ? gcount[2 * t + 1] : 0;
    int pv = c0 + c1;
    int sc = pv;
#pragma unroll
    for (int off = 1; off < 64; off <<= 1) {
        int u = __shfl_up(sc, off, 64);
        if ((t & 63) >= off) sc += u;
    }
    if ((t & 63) == 63) wsum[t >> 6] = sc;
    __syncthreads();
    if (t < 64) {
        int ws = (t < 16) ? wsum[t] : 0;
#pragma unroll
        for (int off = 1; off < 16; off <<= 1) {
            int u = __shfl_up(ws, off, 64);
            if (t >= off) ws += u;
        }
        if (t < 16) wsum[t] = ws;
    }
    __syncthreads();
    int wid = t >> 6;
    int ex = sc - pv + ((wid > 0) ? wsum[wid - 1] : 0);
    if (2 * t == b) base_sh = ex;
    if (2 * t + 1 == b) base_sh = ex + c0;

    // per-row histogram from registers
#pragma unroll
    for (int k = 0; k < BB_K; ++k)
        if (e[k].x >= 0) atomicAdd(&s[((unsigned)e[k].x) >> 18], 1);
    __syncthreads();
    int base = base_sh;

    int v = (t < RB) ? s[t] : 0;
    int sc2 = v;
#pragma unroll
    for (int off = 1; off < 64; off <<= 1) {
        int u = __shfl_up(sc2, off, 64);
        if ((t & 63) >= off) sc2 += u;
    }
    if ((t & 63) == 63) wsum[t >> 6] = sc2;
    __syncthreads();
    if (t < 64) {
        int ws = (t < 16) ? wsum[t] : 0;
#pragma unroll
        for (int off = 1; off < 16; off <<= 1) {
            int u = __shfl_up(ws, off, 64);
            if (t >= off) ws += u;
        }
        if (t < 16) wsum[t] = ws;
    }
    __syncthreads();
    int wid2 = t >> 6;
    int excl = sc2 - v + ((wid2 > 0) ? wsum[wid2 - 1] : 0);

    int row = (b << RB_SHIFT) + t;
    if (t < RB) {
        if (row < N_NODES) row_ptr[row] = base + excl;
        cur[t] = excl;
    }
    if (b == NB - 1 && t == 0) row_ptr[N_NODES] = NNZ;
    __syncthreads();
    // counting-sort from registers into LDS
#pragma unroll
    for (int k = 0; k < BB_K; ++k) {
        if (e[k].x >= 0) {
            int rl = ((unsigned)e[k].x) >> 18;
            int pos = atomicAdd(&cur[rl], 1);
            sorted[pos] = make_int2(e[k].x & ((1 << 18) - 1), e[k].y);
        }
    }
    __syncthreads();
    // sequential coalesced copy-out
    for (int i = t; i < cnt; i += 1024)
        edges[base + i] = sorted[i];
}

// ---------------- fused 3-layer SpMM + perturbation + mean ----------------
// Persistent: 1792 blocks x 256 thr, zero LDS, VGPR capped by launch_bounds
// (256,8) -> 8 blocks/CU capacity (2048) vs 1792 grid: co-resident with slack.
// Per-row body identical to the known-good 161us/layer kernel. Between layers:
// spread-counter grid barrier (pattern validated rounds 5-6) with release/
// acquire fences -- __threadfence() emits L2 writeback / L1+L2 invalidate, so
// cross-XCD x visibility matches what kernel boundaries provided before.
__global__ __launch_bounds__(256, 8) void spmm_fused(
        uint* __restrict__ xh_a, uint* __restrict__ xh_b,
        const int* __restrict__ row_ptr, const int2* __restrict__ edges,
        const float* __restrict__ noise, float* __restrict__ out,
        int* __restrict__ bar) {
    int lane = threadIdx.x & 63;
    int gw = blockIdx.x * 4 + (threadIdx.x >> 6);
    int g = lane >> 3;        // edge group 0..7
    int sub = lane & 7;       // dim slice: dims [sub*8, sub*8+8)

    const uint* xs = xh_a;
    uint* xd = xh_b;

#pragma unroll
    for (int layer = 0; layer < 3; ++layer) {
        const float* noise_k = noise + (size_t)layer * N_NODES * EMB;
        for (int row = gw; row < N_NODES; row += SPMM_WAVES) {
            int beg = row_ptr[row];
            int end = row_ptr[row + 1];
            int lim = end - 1;

            float a0 = 0.f, a1 = 0.f, a2 = 0.f, a3 = 0.f;
            float a4 = 0.f, a5 = 0.f, a6 = 0.f, a7 = 0.f;

            for (int base = beg; base < end; base += 16) {
                int i0 = base + g, i1 = base + 8 + g;
                int2 e0 = edges[min(i0, lim)];
                int2 e1 = edges[min(i1, lim)];
                const uint4* q0 = (const uint4*)(xs + (long)e0.x * (EMB / 2));
                const uint4* q1 = (const uint4*)(xs + (long)e1.x * (EMB / 2));
                uint4 h0 = q0[sub];                   // 8 bf16 dims, 16B coalesced
                uint4 h1 = q1[sub];
                float w0 = (i0 < end) ? __int_as_float(e0.y) : 0.f;
                float w1 = (i1 < end) ? __int_as_float(e1.y) : 0.f;
                a0 += w0 * bflo(h0.x); a1 += w0 * bfhi(h0.x);
                a2 += w0 * bflo(h0.y); a3 += w0 * bfhi(h0.y);
                a4 += w0 * bflo(h0.z); a5 += w0 * bfhi(h0.z);
                a6 += w0 * bflo(h0.w); a7 += w0 * bfhi(h0.w);
                a0 += w1 * bflo(h1.x); a1 += w1 * bfhi(h1.x);
                a2 += w1 * bflo(h1.y); a3 += w1 * bfhi(h1.y);
                a4 += w1 * bflo(h1.z); a5 += w1 * bfhi(h1.z);
                a6 += w1 * bflo(h1.w); a7 += w1 * bfhi(h1.w);
            }

            // fold the 8 edge-groups (bits 3,4,5 of lane)
#pragma unroll
            for (int off = 8; off <= 32; off <<= 1) {
                a0 += __shfl_xor(a0, off, 64); a1 += __shfl_xor(a1, off, 64);
                a2 += __shfl_xor(a2, off, 64); a3 += __shfl_xor(a3, off, 64);
                a4 += __shfl_xor(a4, off, 64); a5 += __shfl_xor(a5, off, 64);
                a6 += __shfl_xor(a6, off, 64); a7 += __shfl_xor(a7, off, 64);
            }

            // perturbation
            const float4* nz = (const float4*)(noise_k + (long)row * EMB);
            float4 n0 = nz[sub * 2];
            float4 n1 = nz[sub * 2 + 1];
            float ss = n0.x * n0.x + n0.y * n0.y + n0.z * n0.z + n0.w * n0.w
                     + n1.x * n1.x + n1.y * n1.y + n1.z * n1.z + n1.w * n1.w;
            ss += __shfl_xor(ss, 1, 64);
            ss += __shfl_xor(ss, 2, 64);
            ss += __shfl_xor(ss, 4, 64);
            float s = EPS_F / fmaxf(sqrtf(ss), NORM_EPS_F);

            float v0 = a0 + ((a0 > 0.f) ? 1.f : ((a0 < 0.f) ? -1.f : 0.f)) * n0.x * s;
            float v1 = a1 + ((a1 > 0.f) ? 1.f : ((a1 < 0.f) ? -1.f : 0.f)) * n0.y * s;
            float v2 = a2 + ((a2 > 0.f) ? 1.f : ((a2 < 0.f) ? -1.f : 0.f)) * n0.z * s;
            float v3 = a3 + ((a3 > 0.f) ? 1.f : ((a3 < 0.f) ? -1.f : 0.f)) * n0.w * s;
            float v4 = a4 + ((a4 > 0.f) ? 1.f : ((a4 < 0.f) ? -1.f : 0.f)) * n1.x * s;
            float v5 = a5 + ((a5 > 0.f) ? 1.f : ((a5 < 0.f) ? -1.f : 0.f)) * n1.y * s;
            float v6 = a6 + ((a6 > 0.f) ? 1.f : ((a6 < 0.f) ? -1.f : 0.f)) * n1.z * s;
            float v7 = a7 + ((a7 > 0.f) ? 1.f : ((a7 < 0.f) ? -1.f : 0.f)) * n1.w * s;

            if (g == 0) {
                float4* po = (float4*)(out + (long)row * EMB);
                if (layer == 0) {
                    po[sub * 2] = make_float4(v0, v1, v2, v3);
                    po[sub * 2 + 1] = make_float4(v4, v5, v6, v7);
                } else if (layer == 1) {
                    float4 o0 = po[sub * 2], o1 = po[sub * 2 + 1];
                    o0.x += v0; o0.y += v1; o0.z += v2; o0.w += v3;
                    o1.x += v4; o1.y += v5; o1.z += v6; o1.w += v7;
                    po[sub * 2] = o0;
                    po[sub * 2 + 1] = o1;
                } else {
                    float4 o0 = po[sub * 2], o1 = po[sub * 2 + 1];
                    o0.x = (o0.x + v0) * (1.f / 3.f); o0.y = (o0.y + v1) * (1.f / 3.f);
                    o0.z = (o0.z + v2) * (1.f / 3.f); o0.w = (o0.w + v3) * (1.f / 3.f);
                    o1.x = (o1.x + v4) * (1.f / 3.f); o1.y = (o1.y + v5) * (1.f / 3.f);
                    o1.z = (o1.z + v6) * (1.f / 3.f); o1.w = (o1.w + v7) * (1.f / 3.f);
                    po[sub * 2] = o0;
                    po[sub * 2 + 1] = o1;
                }
                if (layer != 2) {
                    uint4* ph = (uint4*)(xd + (long)row * (EMB / 2));
                    ph[sub] = make_uint4(pack2(v0, v1), pack2(v2, v3),
                                         pack2(v4, v5), pack2(v6, v7));
                }
            }
        }

        if (layer < 2) {
            // grid barrier (release/acquire). All waves reach this point:
            // the row loop has no early return.
            __syncthreads();
            if (threadIdx.x == 0) {
                __threadfence();     // release: write back this XCD's L2
                int* bb = bar + layer * BAR_STRIDE;
                __hip_atomic_fetch_add(&bb[(blockIdx.x & 15) << 4], 1,
                                       __ATOMIC_RELEASE, __HIP_MEMORY_SCOPE_AGENT);
                for (;;) {
                    int ssum = 0;
#pragma unroll
                    for (int k = 0; k < 16; ++k)
                        ssum += __hip_atomic_load(&bb[k << 4], __ATOMIC_ACQUIRE,
                                                  __HIP_MEMORY_SCOPE_AGENT);
                    if (ssum >= SPMM_BLOCKS) break;
                    __builtin_amdgcn_s_sleep(8);
                }
                __threadfence();     // acquire: invalidate stale L1/L2 lines
            }
            __syncthreads();
            const uint* tmp = xs;
            xs = xd;
            xd = (uint*)tmp;
        }
    }
}

// ---------------- launch ----------------

extern "C" void kernel_launch(void* const* d_in, const int* in_sizes, int n_in,
                              void* d_out, int out_size, void* d_ws, size_t ws_size,
                              hipStream_t stream) {
    const float* user_emb = (const float*)d_in[0];
    const float* item_emb = (const float*)d_in[1];
    const int*   adj_rows = (const int*)d_in[2];
    const int*   adj_cols = (const int*)d_in[3];
    const float* adj_vals = (const float*)d_in[4];
    const float* noise    = (const float*)d_in[5];
    float* out = (float*)d_out;

    char* ws = (char*)d_ws;
    size_t off = 0;
    auto alloc = [&](size_t bytes) {
        char* p = ws + off;
        off += (bytes + 15) & ~size_t(15);
        return p;
    };
    int*   row_ptr = (int*)alloc((N_NODES + 1) * sizeof(int));
    int*   ctrl    = (int*)alloc((NB + 2 * BAR_STRIDE) * sizeof(int));
    int2*  edges   = (int2*)alloc((size_t)NNZ * sizeof(int2));
    uint*  xh_a    = (uint*)alloc((size_t)N_NODES * EMB * 2);       // 19.2 MB
    int2*  staging = (int2*)alloc((size_t)NB * CAP * sizeof(int2)); // 43.2 MB
    // xh_b aliases staging (staging dead after binB; xh_b first written by
    // layer 0 of the fused spmm, which launches after binB). xh_a is its own
    // region because binA's fused convert writes it while staging is live.
    uint* xh_b = (uint*)staging;

    int* gcount = ctrl;
    int* bar    = ctrl + NB;

    // one memset replaces the init kernel; re-runs on every graph replay so
    // the barrier counters are re-zeroed for rocprof's multi-pass replays.
    hipMemsetAsync(ctrl, 0, (NB + 2 * BAR_STRIDE) * sizeof(int), stream);

    binA_kernel<<<BINA_GRID, 512, 0, stream>>>(adj_rows, adj_cols, adj_vals,
                                               gcount, staging,
                                               (const float4*)user_emb,
                                               (const float4*)item_emb,
                                               (uint2*)xh_a);
    binB_kernel<<<NB, 1024, 0, stream>>>(gcount, staging, edges, row_ptr);

    spmm_fused<<<SPMM_BLOCKS, 256, 0, stream>>>(xh_a, xh_b, row_ptr, edges,
                                                noise, out, bar);
}

// Round 9
// 611.530 us; speedup vs baseline: 3.3722x; 3.3722x over previous
//
#include <hip/hip_runtime.h>

typedef unsigned int uint;

#define USER_NUM   100000
#define ITEM_NUM   50000
#define N_NODES    (USER_NUM + ITEM_NUM)
#define NNZ        4800000
#define EMB        64
#define EPS_F      0.2f
#define NORM_EPS_F 1e-12f

// buckets of 256 rows
#define RB_SHIFT   8
#define RB         256
#define NB         ((N_NODES + RB - 1) / RB)     // 586
#define CAP        9216                           // mean 8191, std ~90 -> +11 sigma
#define BINA_CHUNK 4096
#define BINA_GRID  ((NNZ + BINA_CHUNK - 1) / BINA_CHUNK)  // 1172
#define BB_K       9                              // ceil(CAP / 1024)

// ---------------- bf16 helpers ----------------
__device__ inline float bflo(uint u) { return __uint_as_float(u << 16); }
__device__ inline float bfhi(uint u) { return __uint_as_float(u & 0xffff0000u); }
__device__ inline uint f2bf(float f) {                 // RNE round to bf16
    uint u = __float_as_uint(f);
    return (u + 0x7fffu + ((u >> 16) & 1u)) >> 16;
}
__device__ inline uint pack2(float a, float b) { return f2bf(a) | (f2bf(b) << 16); }

// ---------------- CSR build ----------------

// Phase A: block-level LDS counting sort by bucket (gcount zero-initialized by
// hipMemsetAsync; staging position = b*CAP + fetch-added count). Convert
// (fp32 concat -> bf16 pack) fused as a tail (validated round 8: build phase
// 267 -> 172us with these fusions).
__global__ __launch_bounds__(512) void binA_kernel(const int* __restrict__ rows,
                                                   const int* __restrict__ cols,
                                                   const float* __restrict__ vals,
                                                   int* __restrict__ gcount,
                                                   int2* __restrict__ staging,
                                                   const float4* __restrict__ uemb,
                                                   const float4* __restrict__ iemb,
                                                   uint2* __restrict__ xh) {
    __shared__ int2 data[BINA_CHUNK];            // 32 KB
    __shared__ unsigned short bid[BINA_CHUNK];   // 8 KB
    __shared__ int hist[NB];
    __shared__ int rstart[NB + 1];
    __shared__ int gbase[NB];
    __shared__ int lcur[NB];
    __shared__ int wsum[8];
    int t = threadIdx.x;
    int cbeg = blockIdx.x * BINA_CHUNK;
    int cend = min(cbeg + BINA_CHUNK, NNZ);
    int total = cend - cbeg;

    int r[8], c[8];
    float v[8];
    if (t < NB) hist[t] = 0;
    if (t + 512 < NB) hist[t + 512] = 0;
    __syncthreads();
#pragma unroll
    for (int k = 0; k < 8; ++k) {
        int i = cbeg + (k << 9) + t;
        bool ok = i < cend;
        r[k] = ok ? rows[i] : -1;
        c[k] = ok ? cols[i] : 0;
        v[k] = ok ? vals[i] : 0.f;
    }
#pragma unroll
    for (int k = 0; k < 8; ++k)
        if (r[k] >= 0) atomicAdd(&hist[r[k] >> RB_SHIFT], 1);
    __syncthreads();

    // pair-per-thread hierarchical shfl scan over 1024 slots (NB=586)
    int v0 = (2 * t < NB) ? hist[2 * t] : 0;
    int v1 = (2 * t + 1 < NB) ? hist[2 * t + 1] : 0;
    int pv = v0 + v1;
    int sc = pv;
#pragma unroll
    for (int off = 1; off < 64; off <<= 1) {
        int u = __shfl_up(sc, off, 64);
        if ((t & 63) >= off) sc += u;
    }
    if ((t & 63) == 63) wsum[t >> 6] = sc;
    __syncthreads();
    if (t < 64) {
        int ws = (t < 8) ? wsum[t] : 0;
#pragma unroll
        for (int off = 1; off < 8; off <<= 1) {
            int u = __shfl_up(ws, off, 64);
            if (t >= off) ws += u;
        }
        if (t < 8) wsum[t] = ws;
    }
    __syncthreads();
    int wid = t >> 6;
    int ex = sc - pv + ((wid > 0) ? wsum[wid - 1] : 0);
    if (2 * t <= NB) rstart[2 * t] = ex;
    if (2 * t + 1 <= NB) rstart[2 * t + 1] = ex + v0;
    if (2 * t < NB) {
        gbase[2 * t] = (2 * t) * CAP + atomicAdd(&gcount[2 * t], v0);
        lcur[2 * t] = 0;
    }
    if (2 * t + 1 < NB) {
        gbase[2 * t + 1] = (2 * t + 1) * CAP + atomicAdd(&gcount[2 * t + 1], v1);
        lcur[2 * t + 1] = 0;
    }
    __syncthreads();

    // sort into LDS by bucket, recording bucket id per slot
#pragma unroll
    for (int k = 0; k < 8; ++k) {
        if (r[k] >= 0) {
            int b = r[k] >> RB_SHIFT;
            int pos = rstart[b] + atomicAdd(&lcur[b], 1);
            data[pos] = make_int2(((r[k] & (RB - 1)) << 18) | c[k],
                                  __float_as_int(v[k]));
            bid[pos] = (unsigned short)b;
        }
    }
    __syncthreads();

    // sequential copy-out: consecutive threads -> consecutive global addresses
    for (int i = t; i < total; i += 512) {
        int b = bid[i];
        staging[(long)gbase[b] + (i - rstart[b])] = data[i];
    }

    // ---- fused convert tail (independent work, no barrier needed) ----
    const int NU4 = USER_NUM * EMB / 4;
    const int NT4 = N_NODES * EMB / 4;
    int stride = gridDim.x * blockDim.x;
    for (int i = blockIdx.x * blockDim.x + t; i < NT4; i += stride) {
        float4 f = (i < NU4) ? uemb[i] : iemb[i - NU4];
        xh[i] = make_uint2(pack2(f.x, f.y), pack2(f.z, f.w));
    }
}

// Phase B: one 1024-thread block per 256-row bucket. Bucket-base prefix sum
// computed in-block (bscan folded in). Staging read once into registers; LDS
// counting sort; sequential coalesced copy-out.
__global__ __launch_bounds__(1024) void binB_kernel(const int* __restrict__ gcount,
                                                    const int2* __restrict__ staging,
                                                    int2* __restrict__ edges,
                                                    int* __restrict__ row_ptr) {
    __shared__ int2 sorted[CAP];      // 72 KB
    __shared__ int s[RB];
    __shared__ int cur[RB];
    __shared__ int wsum[16];
    __shared__ int base_sh;
    int b = blockIdx.x;
    int t = threadIdx.x;
    int cnt = gcount[b];
    long sbase = (long)b * CAP;

    int2 e[BB_K];
    if (t < RB) s[t] = 0;
#pragma unroll
    for (int k = 0; k < BB_K; ++k) {
        int i = (k << 10) + t;
        e[k] = (i < cnt) ? staging[sbase + i] : make_int2(-1, 0);
    }

    // in-block exclusive scan of bucket counts -> base for this bucket
    int c0 = (2 * t < NB) ? gcount[2 * t] : 0;
    int c1 = (2 * t + 1 < NB) ? gcount[2 * t + 1] : 0;
    int pv = c0 + c1;
    int sc = pv;
#pragma unroll
    for (int off = 1; off < 64; off <<= 1) {
        int u = __shfl_up(sc, off, 64);
        if ((t & 63) >= off) sc += u;
    }
    if ((t & 63) == 63) wsum[t >> 6] = sc;
    __syncthreads();
    if (t < 64) {
        int ws = (t < 16) ? wsum[t] : 0;
#pragma unroll
        for (int off = 1; off < 16; off <<= 1) {
            int u = __shfl_up(ws, off, 64);
            if (t >= off) ws += u;
        }
        if (t < 16) wsum[t] = ws;
    }
    __syncthreads();
    int wid = t >> 6;
    int ex = sc - pv + ((wid > 0) ? wsum[wid - 1] : 0);
    if (2 * t == b) base_sh = ex;
    if (2 * t + 1 == b) base_sh = ex + c0;

    // per-row histogram from registers
#pragma unroll
    for (int k = 0; k < BB_K; ++k)
        if (e[k].x >= 0) atomicAdd(&s[((unsigned)e[k].x) >> 18], 1);
    __syncthreads();
    int base = base_sh;

    int v = (t < RB) ? s[t] : 0;
    int sc2 = v;
#pragma unroll
    for (int off = 1; off < 64; off <<= 1) {
        int u = __shfl_up(sc2, off, 64);
        if ((t & 63) >= off) sc2 += u;
    }
    if ((t & 63) == 63) wsum[t >> 6] = sc2;
    __syncthreads();
    if (t < 64) {
        int ws = (t < 16) ? wsum[t] : 0;
#pragma unroll
        for (int off = 1; off < 16; off <<= 1) {
            int u = __shfl_up(ws, off, 64);
            if (t >= off) ws += u;
        }
        if (t < 16) wsum[t] = ws;
    }
    __syncthreads();
    int wid2 = t >> 6;
    int excl = sc2 - v + ((wid2 > 0) ? wsum[wid2 - 1] : 0);

    int row = (b << RB_SHIFT) + t;
    if (t < RB) {
        if (row < N_NODES) row_ptr[row] = base + excl;
        cur[t] = excl;
    }
    if (b == NB - 1 && t == 0) row_ptr[N_NODES] = NNZ;
    __syncthreads();
    // counting-sort from registers into LDS
#pragma unroll
    for (int k = 0; k < BB_K; ++k) {
        if (e[k].x >= 0) {
            int rl = ((unsigned)e[k].x) >> 18;
            int pos = atomicAdd(&cur[rl], 1);
            sorted[pos] = make_int2(e[k].x & ((1 << 18) - 1), e[k].y);
        }
    }
    __syncthreads();
    // sequential coalesced copy-out
    for (int i = t; i < cnt; i += 1024)
        edges[base + i] = sorted[i];
}

// ---------------- SpMM (bf16 gather) + perturbation + mean ----------------
// Known-good kernel (161us/layer, 3.86 TB/s). One wave per row; 8 groups of 8
// lanes; 2 edges in flight per lane. SEPARATE DISPATCH PER LAYER: round-8's
// persistent fused version (grid barrier between layers) ran 4x slower
// (VALUBusy 10%) -- in-kernel grid sync loses badly to kernel boundaries at
// this phase size. Rounds 4-6 L2-phasing also lost despite halving traffic.
// mode 0: out = v ; mode 1: out += v ; mode 2: out = (out+v)/3
__global__ __launch_bounds__(256) void spmm_layer_kernel(const uint* __restrict__ x,
                                                         uint* __restrict__ x_out,
                                                         const int* __restrict__ row_ptr,
                                                         const int2* __restrict__ edges,
                                                         const float* __restrict__ noise_k,
                                                         float* __restrict__ out, int mode) {
    int lane = threadIdx.x & 63;
    int row = blockIdx.x * 4 + (threadIdx.x >> 6);
    if (row >= N_NODES) return;
    int g = lane >> 3;        // edge group 0..7
    int sub = lane & 7;       // dim slice: dims [sub*8, sub*8+8)

    int beg = row_ptr[row];
    int end = row_ptr[row + 1];
    int lim = end - 1;

    float a0 = 0.f, a1 = 0.f, a2 = 0.f, a3 = 0.f;
    float a4 = 0.f, a5 = 0.f, a6 = 0.f, a7 = 0.f;

    for (int base = beg; base < end; base += 16) {
        int i0 = base + g, i1 = base + 8 + g;
        int2 e0 = edges[min(i0, lim)];
        int2 e1 = edges[min(i1, lim)];
        const uint4* q0 = (const uint4*)(x + (long)e0.x * (EMB / 2));
        const uint4* q1 = (const uint4*)(x + (long)e1.x * (EMB / 2));
        uint4 h0 = q0[sub];                       // 8 bf16 dims, 16B coalesced
        uint4 h1 = q1[sub];
        float w0 = (i0 < end) ? __int_as_float(e0.y) : 0.f;
        float w1 = (i1 < end) ? __int_as_float(e1.y) : 0.f;
        a0 += w0 * bflo(h0.x); a1 += w0 * bfhi(h0.x);
        a2 += w0 * bflo(h0.y); a3 += w0 * bfhi(h0.y);
        a4 += w0 * bflo(h0.z); a5 += w0 * bfhi(h0.z);
        a6 += w0 * bflo(h0.w); a7 += w0 * bfhi(h0.w);
        a0 += w1 * bflo(h1.x); a1 += w1 * bfhi(h1.x);
        a2 += w1 * bflo(h1.y); a3 += w1 * bfhi(h1.y);
        a4 += w1 * bflo(h1.z); a5 += w1 * bfhi(h1.z);
        a6 += w1 * bflo(h1.w); a7 += w1 * bfhi(h1.w);
    }

    // fold the 8 edge-groups (bits 3,4,5 of lane)
#pragma unroll
    for (int off = 8; off <= 32; off <<= 1) {
        a0 += __shfl_xor(a0, off, 64); a1 += __shfl_xor(a1, off, 64);
        a2 += __shfl_xor(a2, off, 64); a3 += __shfl_xor(a3, off, 64);
        a4 += __shfl_xor(a4, off, 64); a5 += __shfl_xor(a5, off, 64);
        a6 += __shfl_xor(a6, off, 64); a7 += __shfl_xor(a7, off, 64);
    }

    // perturbation: v = acc + sign(acc) * (r/max(||r||,eps)) * EPS  (fp32 noise)
    const float4* nz = (const float4*)(noise_k + (long)row * EMB);
    float4 n0 = nz[sub * 2];
    float4 n1 = nz[sub * 2 + 1];
    float ss = n0.x * n0.x + n0.y * n0.y + n0.z * n0.z + n0.w * n0.w
             + n1.x * n1.x + n1.y * n1.y + n1.z * n1.z + n1.w * n1.w;
    ss += __shfl_xor(ss, 1, 64);
    ss += __shfl_xor(ss, 2, 64);
    ss += __shfl_xor(ss, 4, 64);
    float s = EPS_F / fmaxf(sqrtf(ss), NORM_EPS_F);

    float v0 = a0 + ((a0 > 0.f) ? 1.f : ((a0 < 0.f) ? -1.f : 0.f)) * n0.x * s;
    float v1 = a1 + ((a1 > 0.f) ? 1.f : ((a1 < 0.f) ? -1.f : 0.f)) * n0.y * s;
    float v2 = a2 + ((a2 > 0.f) ? 1.f : ((a2 < 0.f) ? -1.f : 0.f)) * n0.z * s;
    float v3 = a3 + ((a3 > 0.f) ? 1.f : ((a3 < 0.f) ? -1.f : 0.f)) * n0.w * s;
    float v4 = a4 + ((a4 > 0.f) ? 1.f : ((a4 < 0.f) ? -1.f : 0.f)) * n1.x * s;
    float v5 = a5 + ((a5 > 0.f) ? 1.f : ((a5 < 0.f) ? -1.f : 0.f)) * n1.y * s;
    float v6 = a6 + ((a6 > 0.f) ? 1.f : ((a6 < 0.f) ? -1.f : 0.f)) * n1.z * s;
    float v7 = a7 + ((a7 > 0.f) ? 1.f : ((a7 < 0.f) ? -1.f : 0.f)) * n1.w * s;

    if (g == 0) {
        float4* po = (float4*)(out + (long)row * EMB);
        float4 f01 = make_float4(v0, v1, v2, v3);
        float4 f23 = make_float4(v4, v5, v6, v7);
        if (mode == 0) {
            po[sub * 2] = f01;
            po[sub * 2 + 1] = f23;
        } else if (mode == 1) {
            float4 o0 = po[sub * 2], o1 = po[sub * 2 + 1];
            o0.x += v0; o0.y += v1; o0.z += v2; o0.w += v3;
            o1.x += v4; o1.y += v5; o1.z += v6; o1.w += v7;
            po[sub * 2] = o0;
            po[sub * 2 + 1] = o1;
        } else {
            float4 o0 = po[sub * 2], o1 = po[sub * 2 + 1];
            o0.x = (o0.x + v0) * (1.f / 3.f); o0.y = (o0.y + v1) * (1.f / 3.f);
            o0.z = (o0.z + v2) * (1.f / 3.f); o0.w = (o0.w + v3) * (1.f / 3.f);
            o1.x = (o1.x + v4) * (1.f / 3.f); o1.y = (o1.y + v5) * (1.f / 3.f);
            o1.z = (o1.z + v6) * (1.f / 3.f); o1.w = (o1.w + v7) * (1.f / 3.f);
            po[sub * 2] = o0;
            po[sub * 2 + 1] = o1;
        }
        if (mode != 2) {
            uint4* ph = (uint4*)(x_out + (long)row * (EMB / 2));
            ph[sub] = make_uint4(pack2(v0, v1), pack2(v2, v3),
                                 pack2(v4, v5), pack2(v6, v7));
        }
    }
}

// ---------------- launch ----------------

extern "C" void kernel_launch(void* const* d_in, const int* in_sizes, int n_in,
                              void* d_out, int out_size, void* d_ws, size_t ws_size,
                              hipStream_t stream) {
    const float* user_emb = (const float*)d_in[0];
    const float* item_emb = (const float*)d_in[1];
    const int*   adj_rows = (const int*)d_in[2];
    const int*   adj_cols = (const int*)d_in[3];
    const float* adj_vals = (const float*)d_in[4];
    const float* noise    = (const float*)d_in[5];
    float* out = (float*)d_out;

    char* ws = (char*)d_ws;
    size_t off = 0;
    auto alloc = [&](size_t bytes) {
        char* p = ws + off;
        off += (bytes + 15) & ~size_t(15);
        return p;
    };
    int*   row_ptr = (int*)alloc((N_NODES + 1) * sizeof(int));
    int*   gcount  = (int*)alloc(NB * sizeof(int));
    int2*  edges   = (int2*)alloc((size_t)NNZ * sizeof(int2));
    uint*  xh_a    = (uint*)alloc((size_t)N_NODES * EMB * 2);       // 19.2 MB
    int2*  staging = (int2*)alloc((size_t)NB * CAP * sizeof(int2)); // 43.2 MB
    // xh_b aliases staging (staging dead after binB; xh_b first written by
    // spmm layer 0, which launches after binB). xh_a is its own region because
    // binA's fused convert writes it while staging is live.
    uint* xh_b = (uint*)staging;

    // ---- CSR build (memset + 2 kernels; fusions validated round 8) ----
    hipMemsetAsync(gcount, 0, NB * sizeof(int), stream);
    binA_kernel<<<BINA_GRID, 512, 0, stream>>>(adj_rows, adj_cols, adj_vals,
                                               gcount, staging,
                                               (const float4*)user_emb,
                                               (const float4*)item_emb,
                                               (uint2*)xh_a);
    binB_kernel<<<NB, 1024, 0, stream>>>(gcount, staging, edges, row_ptr);

    // ---- 3 layers (separate dispatches; known-good) ----
    const int LGRID = (N_NODES + 3) / 4;
    const size_t NE = (size_t)N_NODES * EMB;
    spmm_layer_kernel<<<LGRID, 256, 0, stream>>>(xh_a, xh_b, row_ptr, edges,
                                                 noise + 0 * NE, out, 0);
    spmm_layer_kernel<<<LGRID, 256, 0, stream>>>(xh_b, xh_a, row_ptr, edges,
                                                 noise + 1 * NE, out, 1);
    spmm_layer_kernel<<<LGRID, 256, 0, stream>>>(xh_a, nullptr, row_ptr, edges,
                                                 noise + 2 * NE, out, 2);
}